// Round 1
// baseline (909.553 us; speedup 1.0000x reference)
//
#include <hip/hip_runtime.h>
#include <math.h>

#define L_LEN 2001
#define GRID_N 200
#define CCH 1024         // chunk of positions per LDS pass
#define XSTR 1040        // CCH + 16 halo/pad
#define PADX 8           // xs index = local_p + PADX
#define PADY 6           // y1 index = local_p + PADY (6 so conv2 tap windows are 16B-aligned)

__device__ __forceinline__ float fast_rcp(float x) { return __builtin_amdgcn_rcpf(x); }
__device__ __forceinline__ float sigmf(float x) { return fast_rcp(1.0f + __expf(-x)); }

__global__ __launch_bounds__(256, 3)
void taylor_cnn_v8_kernel(const float* __restrict__ phase, const float* __restrict__ primary,
                          const float* __restrict__ secondary, const float* __restrict__ oddeven,
                          const float* __restrict__ pA, const float* __restrict__ pBp,
                          const float* __restrict__ pT0,
                          const float* __restrict__ bng, const float* __restrict__ bnb,
                          const float* __restrict__ bnm, const float* __restrict__ bnv,
                          const float* __restrict__ w1, const float* __restrict__ b1,
                          const float* __restrict__ w2, const float* __restrict__ b2,
                          const float* __restrict__ fcw, const float* __restrict__ fcb,
                          float* __restrict__ out, int nrows)
{
    __shared__ __align__(16) float xs[4][XSTR];    // BN'ed inputs (+gate), zero-padded halo
    __shared__ __align__(16) float y1s[8][XSTR];   // conv1 output (relu'ed), zero-padded
    __shared__ float red[4][20];

    const int tid = threadIdx.x;
    const int row = blockIdx.x;
    if (row >= nrows) return;
    const long base = (long)row * L_LEN;

    const float A  = pA[0];
    const float Bp = pBp[0];
    const float t0 = pT0[0];
    const float A_abs = fabsf(A) + 1e-8f;
    const float rAabs = 1.0f / A_abs;   // hoisted precise reciprocal

    float inv[4], off[4];
#pragma unroll
    for (int c = 0; c < 4; ++c) {
        float iv = bng[c] / sqrtf(bnv[c] + 1e-5f);
        inv[c] = iv;
        off[c] = bnb[c] - bnm[c] * iv;
    }

    // zero the y1 pad cells conv1 never writes: idx [0,4) and [CCH+8, XSTR)
    if (tid < 96) {
        int ch = tid / 12, k = tid % 12;
        int idx = (k < 4) ? k : (CCH + 8 + (k - 4));
        y1s[ch][idx] = 0.0f;
    }

    float s2[16];
#pragma unroll
    for (int i = 0; i < 16; ++i) s2[i] = 0.0f;
    float s_ing = 0.0f, s_fb = 0.0f;

    for (int c0 = 0; c0 < L_LEN; c0 += CCH) {   // c0 = 0, 1024
        __syncthreads();  // prev chunk's conv1 (xs reads) and conv2 (y1 reads) done

        // ---- phase A: global load + gate + BN -> xs; soft-mask sigmoid sums on core ----
        for (int m = tid; m < XSTR; m += 256) {
            int g = c0 + m - PADX;
            float x0 = 0.f, x1 = 0.f, x2 = 0.f, x3 = 0.f;
            if (g >= 0 && g < L_LEN) {
                float ph = phase[base + g];
                float pf = primary[base + g];
                float sf = secondary[base + g];
                float oe = oddeven[base + g];
                float d  = ph - t0;
                float gate = -A * fmaxf(1.0f - Bp * d * d, 0.0f);
                x0 = gate * inv[0] + off[0];
                x1 = pf   * inv[1] + off[1];
                x2 = sf   * inv[2] + off[2];
                x3 = oe   * inv[3] + off[3];
                if (m >= PADX && m < PADX + CCH) {   // each global position counted exactly once
                    float depth = fmaxf(-pf, 0.0f);
                    float dn  = depth * rAabs;
                    float dip = sigmf(50.0f * (dn - 0.1f));
                    float fb  = sigmf(50.0f * (dn - 0.8f));
                    float ing = dip - fb;
                    float tot = 1.0f - dip + ing + fb + 1e-8f;
                    float rt  = fast_rcp(tot);
                    s_ing += ing * rt;
                    s_fb  += fb  * rt;
                }
            }
            xs[0][m] = x0; xs[1][m] = x1; xs[2][m] = x2; xs[3][m] = x3;
        }
        __syncthreads();

        // ---- conv1 (4 positions/thread) -> y1s ----
        {
            const int p0 = tid * 4;
            float t1[4][12];
#pragma unroll
            for (int c = 0; c < 4; ++c) {
                const float4* vp = (const float4*)&xs[c][p0 + 4];
                float4 a = vp[0], b = vp[1], cc = vp[2];
                t1[c][0]=a.x;  t1[c][1]=a.y;  t1[c][2]=a.z;  t1[c][3]=a.w;
                t1[c][4]=b.x;  t1[c][5]=b.y;  t1[c][6]=b.z;  t1[c][7]=b.w;
                t1[c][8]=cc.x; t1[c][9]=cc.y; t1[c][10]=cc.z; t1[c][11]=cc.w;
            }
            const int gp = c0 + p0;
#pragma unroll
            for (int oc = 0; oc < 8; ++oc) {
                float a0 = b1[oc], a1 = b1[oc], a2 = b1[oc], a3 = b1[oc];
#pragma unroll
                for (int c = 0; c < 4; ++c) {
#pragma unroll
                    for (int k = 0; k < 7; ++k) {
                        float w = w1[(oc * 4 + c) * 7 + k];   // uniform -> SGPR
                        a0 += w * t1[c][k + 1];
                        a1 += w * t1[c][k + 2];
                        a2 += w * t1[c][k + 3];
                        a3 += w * t1[c][k + 4];
                    }
                }
                float r0 = (gp     < L_LEN) ? fmaxf(a0, 0.f) : 0.f;
                float r1 = (gp + 1 < L_LEN) ? fmaxf(a1, 0.f) : 0.f;
                float r2 = (gp + 2 < L_LEN) ? fmaxf(a2, 0.f) : 0.f;
                float r3 = (gp + 3 < L_LEN) ? fmaxf(a3, 0.f) : 0.f;
                float2* wp = (float2*)&y1s[oc][p0 + PADY];
                wp[0] = make_float2(r0, r1);
                wp[1] = make_float2(r2, r3);
            }
            // halo: local positions -2,-1, CCH, CCH+1
            if (tid < 4) {
                int p  = (tid < 2) ? (tid - 2) : (CCH + tid - 2);
                int gh = c0 + p;
#pragma unroll
                for (int oc = 0; oc < 8; ++oc) {
                    float a = b1[oc];
#pragma unroll
                    for (int c = 0; c < 4; ++c)
#pragma unroll
                        for (int k = 0; k < 7; ++k)
                            a += w1[(oc * 4 + c) * 7 + k] * xs[c][p + k - 3 + PADX];
                    y1s[oc][p + PADY] = (gh >= 0 && gh < L_LEN) ? fmaxf(a, 0.f) : 0.f;
                }
            }
        }
        __syncthreads();

        // ---- conv2 (4 positions/thread), accumulate channel sums ----
        {
            const int p0 = tid * 4;
            float t2[8][8];
#pragma unroll
            for (int c = 0; c < 8; ++c) {
                const float4* vp = (const float4*)&y1s[c][p0 + 4];
                float4 a = vp[0], b = vp[1];
                t2[c][0]=a.x; t2[c][1]=a.y; t2[c][2]=a.z; t2[c][3]=a.w;
                t2[c][4]=b.x; t2[c][5]=b.y; t2[c][6]=b.z; t2[c][7]=b.w;
            }
            const int gp = c0 + p0;
#pragma unroll
            for (int oc = 0; oc < 16; ++oc) {
                float a0 = b2[oc], a1 = b2[oc], a2 = b2[oc], a3 = b2[oc];
#pragma unroll
                for (int c = 0; c < 8; ++c)
#pragma unroll
                    for (int k = 0; k < 5; ++k) {
                        float w = w2[(oc * 8 + c) * 5 + k];   // uniform -> SGPR
                        a0 += w * t2[c][k];
                        a1 += w * t2[c][k + 1];
                        a2 += w * t2[c][k + 2];
                        a3 += w * t2[c][k + 3];
                    }
                float r = 0.f;
                if (gp     < L_LEN) r += fmaxf(a0, 0.f);
                if (gp + 1 < L_LEN) r += fmaxf(a1, 0.f);
                if (gp + 2 < L_LEN) r += fmaxf(a2, 0.f);
                if (gp + 3 < L_LEN) r += fmaxf(a3, 0.f);
                s2[oc] += r;
            }
        }
    }

    // ---- trapz AUC: 200 interpolated samples straight from global (L2-hot) ----
    float s_auc = 0.0f;
    if (tid < GRID_N) {
        float pos = (float)tid * (2000.0f / 199.0f);
        int i0 = (int)pos;
        if (i0 > 2000) i0 = 2000;
        int i1 = (i0 + 1 < L_LEN) ? i0 + 1 : 2000;
        float w  = pos - (float)i0;
        float d0 = fmaxf(-primary[base + i0], 0.f);
        float d1 = fmaxf(-primary[base + i1], 0.f);
        float v  = d0 * (1.0f - w) + d1 * w;
        float wt = (tid == 0 || tid == GRID_N - 1) ? 0.5f : 1.0f;
        s_auc = v * wt;
    }

    // ---- reduce 19 values: wave shuffle then cross-wave via LDS ----
    float vals[19];
#pragma unroll
    for (int i = 0; i < 16; ++i) vals[i] = s2[i];
    vals[16] = s_ing; vals[17] = s_fb; vals[18] = s_auc;

    const int wave = tid >> 6, lane = tid & 63;
#pragma unroll
    for (int i = 0; i < 19; ++i) {
        float v = vals[i];
        v += __shfl_down(v, 32);
        v += __shfl_down(v, 16);
        v += __shfl_down(v, 8);
        v += __shfl_down(v, 4);
        v += __shfl_down(v, 2);
        v += __shfl_down(v, 1);
        if (lane == 0) red[wave][i] = v;
    }
    __syncthreads();

    if (tid == 0) {
        float S[19];
#pragma unroll
        for (int i = 0; i < 19; ++i)
            S[i] = red[0][i] + red[1][i] + red[2][i] + red[3][i];

        float logit = fcb[0];
#pragma unroll
        for (int oc = 0; oc < 16; ++oc)
            logit += (S[oc] / 2001.0f) * fcw[oc];

        float auc_raw  = (float)(2.0 / 199.0) * S[18];
        float auc_norm = auc_raw / A_abs;
        float m_ing = S[16] / 2001.0f;
        float m_fb  = S[17] / 2001.0f;
        float t14   = (S[16] + S[17]) / 2001.0f + 1e-8f;
        float t12   = m_ing / t14;

        logit += Bp       * fcw[16]
               + auc_raw  * fcw[17]
               + auc_norm * fcw[18]
               + t12      * fcw[19]
               + m_fb     * fcw[20];

        out[row] = 1.0f / (1.0f + expf(-logit));
    }
}

extern "C" void kernel_launch(void* const* d_in, const int* in_sizes, int n_in,
                              void* d_out, int out_size, void* d_ws, size_t ws_size,
                              hipStream_t stream) {
    const float* phase     = (const float*)d_in[0];
    const float* primary   = (const float*)d_in[1];
    const float* secondary = (const float*)d_in[2];
    const float* oddeven   = (const float*)d_in[3];
    const float* pA        = (const float*)d_in[4];
    const float* pBp       = (const float*)d_in[5];
    const float* pT0       = (const float*)d_in[6];
    const float* bng       = (const float*)d_in[7];
    const float* bnb       = (const float*)d_in[8];
    const float* bnm       = (const float*)d_in[9];
    const float* bnv       = (const float*)d_in[10];
    const float* w1        = (const float*)d_in[11];
    const float* b1        = (const float*)d_in[12];
    const float* w2        = (const float*)d_in[13];
    const float* b2        = (const float*)d_in[14];
    const float* fcw       = (const float*)d_in[15];
    const float* fcb       = (const float*)d_in[16];
    float* out = (float*)d_out;

    int nrows = in_sizes[0] / L_LEN;   // 8192
    dim3 grid(nrows), block(256);
    hipLaunchKernelGGL(taylor_cnn_v8_kernel, grid, block, 0, stream,
                       phase, primary, secondary, oddeven, pA, pBp, pT0,
                       bng, bnb, bnm, bnv, w1, b1, w2, b2, fcw, fcb, out, nrows);
}

// Round 2
// 420.608 us; speedup vs baseline: 2.1625x; 2.1625x over previous
//
#include <hip/hip_runtime.h>
#include <math.h>

#define L_LEN 2001
#define NT 126            // ceil(2001/16) position tiles of 16
#define XQ 2048           // padded position-record count

typedef __attribute__((ext_vector_type(8))) short bf16x8;
typedef __attribute__((ext_vector_type(4))) float f32x4;

union FragU { unsigned u[4]; bf16x8 v; };

__device__ __forceinline__ unsigned short f2bf(float f) {
    // round-to-nearest-even bf16 (finite inputs only)
    unsigned u = __builtin_bit_cast(unsigned, f);
    u += 0x7fffu + ((u >> 16) & 1u);
    return (unsigned short)(u >> 16);
}
__device__ __forceinline__ float fast_rcp(float x) { return __builtin_amdgcn_rcpf(x); }
__device__ __forceinline__ float sigmf(float x) { return fast_rcp(1.0f + __expf(-x)); }

__global__ __launch_bounds__(256, 3)
void taylor_cnn_v8_mfma(const float* __restrict__ phase, const float* __restrict__ primary,
                        const float* __restrict__ secondary, const float* __restrict__ oddeven,
                        const float* __restrict__ pA, const float* __restrict__ pBp,
                        const float* __restrict__ pT0,
                        const float* __restrict__ bng, const float* __restrict__ bnb,
                        const float* __restrict__ bnm, const float* __restrict__ bnv,
                        const float* __restrict__ w1, const float* __restrict__ b1,
                        const float* __restrict__ w2, const float* __restrict__ b2,
                        const float* __restrict__ fcw, const float* __restrict__ fcb,
                        float* __restrict__ out, int nrows)
{
    // xsi: position-major, 4 channels bf16 packed (8 B/record). xsi[q] = x[q-3] (pad 3)
    __shared__ __align__(16) unsigned int xs_i[XQ * 2];    // 16 KB
    // y1i: position-major, 8 channels bf16 packed (16 B/record). y1i[q] = y1[q-2] (pad 2)
    __shared__ __align__(16) unsigned int y1_i[XQ * 4];    // 32 KB
    __shared__ float redA[4][16];
    __shared__ float redB[4][3];

    const int tid = threadIdx.x;
    const int row = blockIdx.x;
    if (row >= nrows) return;
    const long base = (long)row * L_LEN;

    const int lane = tid & 63;
    const int wid  = tid >> 6;
    const int n    = lane & 15;     // MFMA column (position within tile) / A row index
    const int quad = lane >> 4;     // MFMA k-block (and D row-quad)

    const float A  = pA[0];
    const float Bp = pBp[0];
    const float t0 = pT0[0];
    const float A_abs = fabsf(A) + 1e-8f;
    const float rAabs = 1.0f / A_abs;

    float inv[4], off[4];
#pragma unroll
    for (int c = 0; c < 4; ++c) {
        float iv = bng[c] / sqrtf(bnv[c] + 1e-5f);
        inv[c] = iv;
        off[c] = bnb[c] - bnm[c] * iv;
    }

    // ---- weight fragments (per-lane, once; L2-hot across blocks) ----
    // conv1: K=32, k-slot jp: tap j = quad + 4*(jp>>2), channel c = jp&3; pad tap7 & oc>=8 with 0
    bf16x8 a1;
#pragma unroll
    for (int jp = 0; jp < 8; ++jp) {
        int j = quad + 4 * (jp >> 2);
        int c = jp & 3;
        float v = (n < 8 && j < 7) ? w1[(n * 4 + c) * 7 + j] : 0.0f;
        a1[jp] = (short)f2bf(v);
    }
    // conv2: two MFMAs. MFMA0: tap j = quad (0..3), c = jp. MFMA1: tap j = quad+4 (only 4 real)
    bf16x8 a20, a21;
#pragma unroll
    for (int jp = 0; jp < 8; ++jp) {
        int c = jp;
        float v0 = w2[(n * 8 + c) * 5 + quad];
        int j2 = quad + 4;
        float v1 = (j2 < 5) ? w2[(n * 8 + c) * 5 + j2] : 0.0f;
        a20[jp] = (short)f2bf(v0);
        a21[jp] = (short)f2bf(v1);
    }
    float b1v[4], b2v[4];
#pragma unroll
    for (int r = 0; r < 4; ++r) {
        b1v[r] = b1[(quad * 4 + r) & 7];   // only quad<2 used
        b2v[r] = b2[quad * 4 + r];
    }

    // ================= stage A: pointwise -> xsi; soft-mask sums =================
    float s_ing = 0.0f, s_fb = 0.0f;
    for (int q = tid; q < XQ; q += 256) {
        int p = q - 3;
        unsigned d0 = 0u, d1 = 0u;
        if (p >= 0 && p < L_LEN) {
            float ph = phase[base + p];
            float pf = primary[base + p];
            float sf = secondary[base + p];
            float oe = oddeven[base + p];
            float dd = ph - t0;
            float gate = -A * fmaxf(1.0f - Bp * dd * dd, 0.0f);
            float x0 = gate * inv[0] + off[0];
            float x1 = pf   * inv[1] + off[1];
            float x2 = sf   * inv[2] + off[2];
            float x3 = oe   * inv[3] + off[3];
            d0 = (unsigned)f2bf(x0) | ((unsigned)f2bf(x1) << 16);
            d1 = (unsigned)f2bf(x2) | ((unsigned)f2bf(x3) << 16);
            // soft-mask features (fp32, each p exactly once)
            float depth = fmaxf(-pf, 0.0f);
            float dn  = depth * rAabs;
            float dip = sigmf(50.0f * (dn - 0.1f));
            float fb  = sigmf(50.0f * (dn - 0.8f));
            float ing = dip - fb;
            float tot = 1.0f - dip + ing + fb + 1e-8f;
            float rt  = fast_rcp(tot);
            s_ing += ing * rt;
            s_fb  += fb  * rt;
        }
        *(uint2*)&xs_i[2 * q] = make_uint2(d0, d1);
    }
    // zero y1i records never (or conditionally) written by conv1: [0,2) and [2016, 2048)
    if (tid < 2)  *(uint4*)&y1_i[4 * tid] = make_uint4(0u, 0u, 0u, 0u);
    if (tid < 32) *(uint4*)&y1_i[4 * (2016 + tid)] = make_uint4(0u, 0u, 0u, 0u);

    // trapz AUC samples (fp32, straight from global)
    float s_auc = 0.0f;
    if (tid < 200) {
        float pos = (float)tid * (2000.0f / 199.0f);
        int i0 = (int)pos;
        if (i0 > 2000) i0 = 2000;
        int i1 = (i0 + 1 < L_LEN) ? i0 + 1 : 2000;
        float w  = pos - (float)i0;
        float d0 = fmaxf(-primary[base + i0], 0.f);
        float d1 = fmaxf(-primary[base + i1], 0.f);
        float v  = d0 * (1.0f - w) + d1 * w;
        float wt = (tid == 0 || tid == 199) ? 0.5f : 1.0f;
        s_auc = v * wt;
    }
    __syncthreads();

    // ================= stage B: conv1 via MFMA -> y1i =================
    const f32x4 fz = {0.f, 0.f, 0.f, 0.f};
    for (int t = wid; t < NT; t += 4) {
        int qb = t * 16 + n + quad;                 // record for taps {quad, quad+4}
        uint2 lo = *(const uint2*)&xs_i[2 * qb];
        uint2 hi = *(const uint2*)&xs_i[2 * (qb + 4)];
        FragU bu; bu.u[0] = lo.x; bu.u[1] = lo.y; bu.u[2] = hi.x; bu.u[3] = hi.y;
        f32x4 d = __builtin_amdgcn_mfma_f32_16x16x32_bf16(a1, bu.v, fz, 0, 0, 0);
        if (lane < 32) {                            // rows 0..7 hold oc, rest are zero
            int p = t * 16 + n;
            bool ok = (p < L_LEN);
            float v0 = fmaxf(d[0] + b1v[0], 0.f);
            float v1 = fmaxf(d[1] + b1v[1], 0.f);
            float v2 = fmaxf(d[2] + b1v[2], 0.f);
            float v3 = fmaxf(d[3] + b1v[3], 0.f);
            unsigned w0 = ok ? ((unsigned)f2bf(v0) | ((unsigned)f2bf(v1) << 16)) : 0u;
            unsigned w1_ = ok ? ((unsigned)f2bf(v2) | ((unsigned)f2bf(v3) << 16)) : 0u;
            *(uint2*)&y1_i[4 * (p + 2) + 2 * quad] = make_uint2(w0, w1_);
        }
    }
    __syncthreads();

    // ================= stage C: conv2 via MFMA, channel sums =================
    float m0 = 0.f, m1 = 0.f, m2 = 0.f, m3 = 0.f;
    for (int t = wid; t < NT; t += 4) {
        int qb = t * 16 + n + quad;
        uint4 r0 = *(const uint4*)&y1_i[4 * qb];         // tap quad, 8 channels
        uint4 r1 = *(const uint4*)&y1_i[4 * (qb + 4)];   // tap quad+4
        FragU u0, u1;
        u0.u[0] = r0.x; u0.u[1] = r0.y; u0.u[2] = r0.z; u0.u[3] = r0.w;
        u1.u[0] = r1.x; u1.u[1] = r1.y; u1.u[2] = r1.z; u1.u[3] = r1.w;
        f32x4 d = __builtin_amdgcn_mfma_f32_16x16x32_bf16(a20, u0.v, fz, 0, 0, 0);
        d = __builtin_amdgcn_mfma_f32_16x16x32_bf16(a21, u1.v, d, 0, 0, 0);
        int p = t * 16 + n;
        float msk = (p < L_LEN) ? 1.0f : 0.0f;
        m0 = fmaf(fmaxf(d[0] + b2v[0], 0.f), msk, m0);
        m1 = fmaf(fmaxf(d[1] + b2v[1], 0.f), msk, m1);
        m2 = fmaf(fmaxf(d[2] + b2v[2], 0.f), msk, m2);
        m3 = fmaf(fmaxf(d[3] + b2v[3], 0.f), msk, m3);
    }

    // ---- reductions ----
    // oc sums: reduce across the 16 position-lanes sharing this quad
#pragma unroll
    for (int dlt = 8; dlt >= 1; dlt >>= 1) {
        m0 += __shfl_xor(m0, dlt);
        m1 += __shfl_xor(m1, dlt);
        m2 += __shfl_xor(m2, dlt);
        m3 += __shfl_xor(m3, dlt);
    }
    if ((lane & 15) == 0) {
        redA[wid][quad * 4 + 0] = m0;
        redA[wid][quad * 4 + 1] = m1;
        redA[wid][quad * 4 + 2] = m2;
        redA[wid][quad * 4 + 3] = m3;
    }
    // full-wave sums for s_ing, s_fb, s_auc
#pragma unroll
    for (int dlt = 32; dlt >= 1; dlt >>= 1) {
        s_ing += __shfl_xor(s_ing, dlt);
        s_fb  += __shfl_xor(s_fb,  dlt);
        s_auc += __shfl_xor(s_auc, dlt);
    }
    if (lane == 0) {
        redB[wid][0] = s_ing;
        redB[wid][1] = s_fb;
        redB[wid][2] = s_auc;
    }
    __syncthreads();

    if (tid == 0) {
        float logit = fcb[0];
#pragma unroll
        for (int oc = 0; oc < 16; ++oc) {
            float s = redA[0][oc] + redA[1][oc] + redA[2][oc] + redA[3][oc];
            logit += (s / 2001.0f) * fcw[oc];
        }
        float Sing = redB[0][0] + redB[1][0] + redB[2][0] + redB[3][0];
        float Sfb  = redB[0][1] + redB[1][1] + redB[2][1] + redB[3][1];
        float Sauc = redB[0][2] + redB[1][2] + redB[2][2] + redB[3][2];

        float auc_raw  = (float)(2.0 / 199.0) * Sauc;
        float auc_norm = auc_raw / A_abs;
        float m_ing = Sing / 2001.0f;
        float m_fb  = Sfb  / 2001.0f;
        float t14   = (Sing + Sfb) / 2001.0f + 1e-8f;
        float t12   = m_ing / t14;

        logit += Bp       * fcw[16]
               + auc_raw  * fcw[17]
               + auc_norm * fcw[18]
               + t12      * fcw[19]
               + m_fb     * fcw[20];

        out[row] = 1.0f / (1.0f + expf(-logit));
    }
}

extern "C" void kernel_launch(void* const* d_in, const int* in_sizes, int n_in,
                              void* d_out, int out_size, void* d_ws, size_t ws_size,
                              hipStream_t stream) {
    const float* phase     = (const float*)d_in[0];
    const float* primary   = (const float*)d_in[1];
    const float* secondary = (const float*)d_in[2];
    const float* oddeven   = (const float*)d_in[3];
    const float* pA        = (const float*)d_in[4];
    const float* pBp       = (const float*)d_in[5];
    const float* pT0       = (const float*)d_in[6];
    const float* bng       = (const float*)d_in[7];
    const float* bnb       = (const float*)d_in[8];
    const float* bnm       = (const float*)d_in[9];
    const float* bnv       = (const float*)d_in[10];
    const float* w1        = (const float*)d_in[11];
    const float* b1        = (const float*)d_in[12];
    const float* w2        = (const float*)d_in[13];
    const float* b2        = (const float*)d_in[14];
    const float* fcw       = (const float*)d_in[15];
    const float* fcb       = (const float*)d_in[16];
    float* out = (float*)d_out;

    int nrows = in_sizes[0] / L_LEN;   // 8192
    dim3 grid(nrows), block(256);
    hipLaunchKernelGGL(taylor_cnn_v8_mfma, grid, block, 0, stream,
                       phase, primary, secondary, oddeven, pA, pBp, pT0,
                       bng, bnb, bnm, bnv, w1, b1, w2, b2, fcw, fcb, out, nrows);
}

// Round 3
// 315.303 us; speedup vs baseline: 2.8847x; 1.3340x over previous
//
#include <hip/hip_runtime.h>
#include <math.h>

#define L_LEN 2001
#define CCH 1024          // positions per chunk
#define XREC 1056         // xs records per chunk: p in [c0-16, c0+1040)
#define NT1 65            // conv1 tiles: y1 p in [c0-8, c0+1032)
#define NT2 64            // conv2 tiles: out p in [c0, c0+1024)

typedef __attribute__((ext_vector_type(8))) short bf16x8;
typedef __attribute__((ext_vector_type(4))) float f32x4;

union FragU { unsigned u[4]; bf16x8 v; };

__device__ __forceinline__ unsigned short f2bf(float f) {
    unsigned u = __builtin_bit_cast(unsigned, f);
    u += 0x7fffu + ((u >> 16) & 1u);
    return (unsigned short)(u >> 16);
}
// pack two fp32 -> bf16 pair (RNE), hi<<16 | lo, via v_perm_b32
__device__ __forceinline__ unsigned bfpack(float lo, float hi) {
    unsigned ul = __builtin_bit_cast(unsigned, lo);
    unsigned uh = __builtin_bit_cast(unsigned, hi);
    ul += 0x7fffu + ((ul >> 16) & 1u);
    uh += 0x7fffu + ((uh >> 16) & 1u);
    return __builtin_amdgcn_perm(uh, ul, 0x07060302);
}
__device__ __forceinline__ float fast_rcp(float x) { return __builtin_amdgcn_rcpf(x); }
__device__ __forceinline__ float sigmf(float x) { return fast_rcp(1.0f + __expf(-x)); }

__global__ __launch_bounds__(256, 6)
void taylor_cnn_v8_mfma(const float* __restrict__ phase, const float* __restrict__ primary,
                        const float* __restrict__ secondary, const float* __restrict__ oddeven,
                        const float* __restrict__ pA, const float* __restrict__ pBp,
                        const float* __restrict__ pT0,
                        const float* __restrict__ bng, const float* __restrict__ bnb,
                        const float* __restrict__ bnm, const float* __restrict__ bnv,
                        const float* __restrict__ w1, const float* __restrict__ b1,
                        const float* __restrict__ w2, const float* __restrict__ b2,
                        const float* __restrict__ fcw, const float* __restrict__ fcb,
                        float* __restrict__ out, int nrows)
{
    // xs: position-major, 4 ch bf16 (8 B/record). record m = position c0 + m - 16
    __shared__ __align__(16) unsigned int xs_i[XREC * 2];   // 8.4 KB
    // y1: position-major, 8 ch bf16 (16 B/record). record q = position c0 + q - 8
    __shared__ __align__(16) unsigned int y1_i[XREC * 4];   // 16.9 KB
    __shared__ float redA[4][16];
    __shared__ float redB[4][3];

    const int tid = threadIdx.x;
    const int row = blockIdx.x;
    if (row >= nrows) return;
    const long base = (long)row * L_LEN;

    const int lane = tid & 63;
    const int wid  = tid >> 6;
    const int n    = lane & 15;     // MFMA column (position in tile)
    const int quad = lane >> 4;     // MFMA k-block / D row-quad

    const float A  = pA[0];
    const float Bp = pBp[0];
    const float t0 = pT0[0];
    const float A_abs = fabsf(A) + 1e-8f;
    const float rAabs = 1.0f / A_abs;

    float inv[4], off[4];
#pragma unroll
    for (int c = 0; c < 4; ++c) {
        float iv = bng[c] / sqrtf(bnv[c] + 1e-5f);
        inv[c] = iv;
        off[c] = bnb[c] - bnm[c] * iv;
    }

    // ---- per-lane weight fragments ----
    // conv1: k-slot jp -> tap j = quad + 4*(jp>>2), ch c = jp&3; zero for j==7 or oc(n)>=8
    bf16x8 a1;
#pragma unroll
    for (int jp = 0; jp < 8; ++jp) {
        int j = quad + 4 * (jp >> 2);
        int c = jp & 3;
        float v = (n < 8 && j < 7) ? w1[(n * 4 + c) * 7 + j] : 0.0f;
        a1[jp] = (short)f2bf(v);
    }
    // conv2: MFMA0 tap j=quad, MFMA1 tap j=quad+4 (real only for quad==0)
    bf16x8 a20, a21;
#pragma unroll
    for (int jp = 0; jp < 8; ++jp) {
        float v0 = w2[(n * 8 + jp) * 5 + quad];
        float v1 = (quad + 4 < 5) ? w2[(n * 8 + jp) * 5 + quad + 4] : 0.0f;
        a20[jp] = (short)f2bf(v0);
        a21[jp] = (short)f2bf(v1);
    }
    float b1v[4], b2v[4];
#pragma unroll
    for (int r = 0; r < 4; ++r) {
        b1v[r] = b1[(quad * 4 + r) & 7];
        b2v[r] = b2[quad * 4 + r];
    }

    float s_ing = 0.0f, s_fb = 0.0f;
    float m0 = 0.f, m1 = 0.f, m2 = 0.f, m3 = 0.f;
    const f32x4 fz = {0.f, 0.f, 0.f, 0.f};

    // ---- stage A: pointwise -> xs; soft-mask sums (core records only) ----
    auto stageA = [&](int c0) {
        for (int m = tid; m < XREC; m += 256) {
            int p = c0 + m - 16;
            unsigned d0 = 0u, d1 = 0u;
            if (p >= 0 && p < L_LEN) {
                float ph = phase[base + p];
                float pf = primary[base + p];
                float sf = secondary[base + p];
                float oe = oddeven[base + p];
                float dd = ph - t0;
                float gate = -A * fmaxf(1.0f - Bp * dd * dd, 0.0f);
                d0 = bfpack(gate * inv[0] + off[0], pf * inv[1] + off[1]);
                d1 = bfpack(sf   * inv[2] + off[2], oe * inv[3] + off[3]);
                if (m >= 16 && m < 16 + CCH) {       // each p counted exactly once
                    float depth = fmaxf(-pf, 0.0f);
                    float dn  = depth * rAabs;
                    float dip = sigmf(50.0f * (dn - 0.1f));
                    float fb  = sigmf(50.0f * (dn - 0.8f));
                    float ing = dip - fb;
                    float tot = 1.0f - dip + ing + fb + 1e-8f;
                    float rt  = fast_rcp(tot);
                    s_ing += ing * rt;
                    s_fb  += fb  * rt;
                }
            }
            *(uint2*)&xs_i[2 * m] = make_uint2(d0, d1);
        }
    };

    // ---- stage B: conv1 via MFMA -> y1 (covers p in [c0-8, c0+1032)) ----
    auto stageB = [&](int c0) {
        for (int t = wid; t < NT1; t += 4) {
            int qb = 16 * t + n + quad + 5;          // xs record for taps {quad, quad+4}
            uint2 lo = *(const uint2*)&xs_i[2 * qb];
            uint2 hi = *(const uint2*)&xs_i[2 * (qb + 4)];
            FragU bu; bu.u[0] = lo.x; bu.u[1] = lo.y; bu.u[2] = hi.x; bu.u[3] = hi.y;
            f32x4 d = __builtin_amdgcn_mfma_f32_16x16x32_bf16(a1, bu.v, fz, 0, 0, 0);
            if (lane < 32) {                          // D rows 0..7 hold the 8 oc
                int p = c0 - 8 + 16 * t + n;
                bool ok = (p >= 0 && p < L_LEN);
                unsigned w0 = 0u, w1_ = 0u;
                if (ok) {
                    w0  = bfpack(fmaxf(d[0] + b1v[0], 0.f), fmaxf(d[1] + b1v[1], 0.f));
                    w1_ = bfpack(fmaxf(d[2] + b1v[2], 0.f), fmaxf(d[3] + b1v[3], 0.f));
                }
                *(uint2*)&y1_i[4 * (16 * t + n) + 2 * quad] = make_uint2(w0, w1_);
            }
        }
    };

    // ---- stage C: conv2 via MFMA, accumulate channel sums ----
    auto stageC = [&](int c0) {
        for (int t = wid; t < NT2; t += 4) {
            int q = 16 * t + n + quad + 6;            // y1 record for taps {quad, quad+4}
            uint4 r0 = *(const uint4*)&y1_i[4 * q];
            uint4 r1 = *(const uint4*)&y1_i[4 * (q + 4)];
            FragU u0, u1;
            u0.u[0] = r0.x; u0.u[1] = r0.y; u0.u[2] = r0.z; u0.u[3] = r0.w;
            u1.u[0] = r1.x; u1.u[1] = r1.y; u1.u[2] = r1.z; u1.u[3] = r1.w;
            f32x4 d = __builtin_amdgcn_mfma_f32_16x16x32_bf16(a20, u0.v, fz, 0, 0, 0);
            d = __builtin_amdgcn_mfma_f32_16x16x32_bf16(a21, u1.v, d, 0, 0, 0);
            int p = c0 + 16 * t + n;
            float msk = (p < L_LEN) ? 1.0f : 0.0f;
            m0 = fmaf(fmaxf(d[0] + b2v[0], 0.f), msk, m0);
            m1 = fmaf(fmaxf(d[1] + b2v[1], 0.f), msk, m1);
            m2 = fmaf(fmaxf(d[2] + b2v[2], 0.f), msk, m2);
            m3 = fmaf(fmaxf(d[3] + b2v[3], 0.f), msk, m3);
        }
    };

    // trapz AUC samples (fp32, straight from global; L2-hot)
    float s_auc = 0.0f;
    if (tid < 200) {
        float pos = (float)tid * (2000.0f / 199.0f);
        int i0 = (int)pos;
        if (i0 > 2000) i0 = 2000;
        int i1 = (i0 + 1 < L_LEN) ? i0 + 1 : 2000;
        float w  = pos - (float)i0;
        float d0 = fmaxf(-primary[base + i0], 0.f);
        float d1 = fmaxf(-primary[base + i1], 0.f);
        float v  = d0 * (1.0f - w) + d1 * w;
        float wt = (tid == 0 || tid == 199) ? 0.5f : 1.0f;
        s_auc = v * wt;
    }

    // ---- pipeline: A0 | B0 | {A1, C0} | B1 | C1 ----
    stageA(0);
    __syncthreads();           // xs(0) ready
    stageB(0);
    __syncthreads();           // y1(0) ready; xs free
    stageA(CCH);               // overlaps with C0 (xs write vs y1 read: disjoint)
    stageC(0);
    __syncthreads();           // xs(1) ready; y1 free
    stageB(CCH);
    __syncthreads();           // y1(1) ready
    stageC(CCH);

    // ---- reductions ----
#pragma unroll
    for (int dlt = 8; dlt >= 1; dlt >>= 1) {
        m0 += __shfl_xor(m0, dlt);
        m1 += __shfl_xor(m1, dlt);
        m2 += __shfl_xor(m2, dlt);
        m3 += __shfl_xor(m3, dlt);
    }
    if ((lane & 15) == 0) {
        redA[wid][quad * 4 + 0] = m0;
        redA[wid][quad * 4 + 1] = m1;
        redA[wid][quad * 4 + 2] = m2;
        redA[wid][quad * 4 + 3] = m3;
    }
#pragma unroll
    for (int dlt = 32; dlt >= 1; dlt >>= 1) {
        s_ing += __shfl_xor(s_ing, dlt);
        s_fb  += __shfl_xor(s_fb,  dlt);
        s_auc += __shfl_xor(s_auc, dlt);
    }
    if (lane == 0) {
        redB[wid][0] = s_ing;
        redB[wid][1] = s_fb;
        redB[wid][2] = s_auc;
    }
    __syncthreads();

    if (tid == 0) {
        float logit = fcb[0];
#pragma unroll
        for (int oc = 0; oc < 16; ++oc) {
            float s = redA[0][oc] + redA[1][oc] + redA[2][oc] + redA[3][oc];
            logit += (s / 2001.0f) * fcw[oc];
        }
        float Sing = redB[0][0] + redB[1][0] + redB[2][0] + redB[3][0];
        float Sfb  = redB[0][1] + redB[1][1] + redB[2][1] + redB[3][1];
        float Sauc = redB[0][2] + redB[1][2] + redB[2][2] + redB[3][2];

        float auc_raw  = (float)(2.0 / 199.0) * Sauc;
        float auc_norm = auc_raw / A_abs;
        float m_ing = Sing / 2001.0f;
        float m_fb  = Sfb  / 2001.0f;
        float t14   = (Sing + Sfb) / 2001.0f + 1e-8f;
        float t12   = m_ing / t14;

        logit += Bp       * fcw[16]
               + auc_raw  * fcw[17]
               + auc_norm * fcw[18]
               + t12      * fcw[19]
               + m_fb     * fcw[20];

        out[row] = 1.0f / (1.0f + expf(-logit));
    }
}

extern "C" void kernel_launch(void* const* d_in, const int* in_sizes, int n_in,
                              void* d_out, int out_size, void* d_ws, size_t ws_size,
                              hipStream_t stream) {
    const float* phase     = (const float*)d_in[0];
    const float* primary   = (const float*)d_in[1];
    const float* secondary = (const float*)d_in[2];
    const float* oddeven   = (const float*)d_in[3];
    const float* pA        = (const float*)d_in[4];
    const float* pBp       = (const float*)d_in[5];
    const float* pT0       = (const float*)d_in[6];
    const float* bng       = (const float*)d_in[7];
    const float* bnb       = (const float*)d_in[8];
    const float* bnm       = (const float*)d_in[9];
    const float* bnv       = (const float*)d_in[10];
    const float* w1        = (const float*)d_in[11];
    const float* b1        = (const float*)d_in[12];
    const float* w2        = (const float*)d_in[13];
    const float* b2        = (const float*)d_in[14];
    const float* fcw       = (const float*)d_in[15];
    const float* fcb       = (const float*)d_in[16];
    float* out = (float*)d_out;

    int nrows = in_sizes[0] / L_LEN;   // 8192
    dim3 grid(nrows), block(256);
    hipLaunchKernelGGL(taylor_cnn_v8_mfma, grid, block, 0, stream,
                       phase, primary, secondary, oddeven, pA, pBp, pT0,
                       bng, bnb, bnm, bnv, w1, b1, w2, b2, fcw, fcb, out, nrows);
}

// Round 4
// 301.486 us; speedup vs baseline: 3.0169x; 1.0458x over previous
//
#include <hip/hip_runtime.h>
#include <math.h>

#define L_LEN 2001
#define CCH 1024          // positions per chunk
#define XREC 1056         // xs/y1 records per chunk

typedef __attribute__((ext_vector_type(8))) short bf16x8;
typedef __attribute__((ext_vector_type(4))) float f32x4;
#if __has_builtin(__builtin_amdgcn_cvt_pk_bf16_f32)
typedef __attribute__((ext_vector_type(2))) __bf16 bf16x2_t;
#endif

union FragU { unsigned u[4]; uint2 u2[2]; uint4 u4; bf16x8 v; };

__device__ __forceinline__ unsigned short f2bf(float f) {
    unsigned u = __builtin_bit_cast(unsigned, f);
    u += 0x7fffu + ((u >> 16) & 1u);
    return (unsigned short)(u >> 16);
}
// pack two fp32 -> bf16 pair (RNE), hi<<16 | lo
__device__ __forceinline__ unsigned bfpack(float lo, float hi) {
#if __has_builtin(__builtin_amdgcn_cvt_pk_bf16_f32)
    bf16x2_t r = __builtin_amdgcn_cvt_pk_bf16_f32(lo, hi);   // S0 -> [15:0]
    return __builtin_bit_cast(unsigned, r);
#else
    unsigned ul = __builtin_bit_cast(unsigned, lo);
    unsigned uh = __builtin_bit_cast(unsigned, hi);
    ul += 0x7fffu + ((ul >> 16) & 1u);
    uh += 0x7fffu + ((uh >> 16) & 1u);
    return __builtin_amdgcn_perm(uh, ul, 0x07060302);
#endif
}
__device__ __forceinline__ float fast_rcp(float x) { return __builtin_amdgcn_rcpf(x); }
__device__ __forceinline__ float fexp2(float x) {
#if __has_builtin(__builtin_amdgcn_exp2f)
    return __builtin_amdgcn_exp2f(x);
#else
    return __expf(x * 0.69314718f);
#endif
}

__global__ __launch_bounds__(256, 6)
void taylor_cnn_v8_mfma(const float* __restrict__ phase, const float* __restrict__ primary,
                        const float* __restrict__ secondary, const float* __restrict__ oddeven,
                        const float* __restrict__ pA, const float* __restrict__ pBp,
                        const float* __restrict__ pT0,
                        const float* __restrict__ bng, const float* __restrict__ bnb,
                        const float* __restrict__ bnm, const float* __restrict__ bnv,
                        const float* __restrict__ w1, const float* __restrict__ b1,
                        const float* __restrict__ w2, const float* __restrict__ b2,
                        const float* __restrict__ fcw, const float* __restrict__ fcb,
                        float* __restrict__ out, int nrows)
{
    // xs: position-major, 4 ch bf16 (8 B/record). record m <-> position c0 + m - 16
    __shared__ __align__(16) unsigned int xs_i[XREC * 2];   // 8.4 KB
    // y1: position-major, 8 ch bf16 (16 B/record). record q <-> position c0 + q - 8
    __shared__ __align__(16) unsigned int y1_i[XREC * 4];   // 16.9 KB
    __shared__ float redA[4][16];
    __shared__ float redB[4][3];

    const int tid = threadIdx.x;
    const int row = blockIdx.x;
    const long base = (long)row * L_LEN;

    const int lane = tid & 63;
    const int wid  = tid >> 6;
    const int n    = lane & 15;     // MFMA column (position in tile)
    const int quad = lane >> 4;     // MFMA k-block / D row-quad

    const float A  = pA[0];
    const float Bp = pBp[0];
    const float t0 = pT0[0];
    const float A_abs = fabsf(A) + 1e-8f;
    const float rAabs = 1.0f / A_abs;
    const float nBp  = -Bp;
    const float cExp = -72.134766f * rAabs;   // -50*log2(e)*rAabs: exp(-50*dn)=exp2(cExp*depth)

    float inv1, inv2, inv3, gInv0, off0, off1, off2, off3;
    {
        float iv0 = bng[0] / sqrtf(bnv[0] + 1e-5f);
        float iv1 = bng[1] / sqrtf(bnv[1] + 1e-5f);
        float iv2 = bng[2] / sqrtf(bnv[2] + 1e-5f);
        float iv3 = bng[3] / sqrtf(bnv[3] + 1e-5f);
        gInv0 = -A * iv0;                     // gate = relu(1-Bp*d^2); x0 = gate*(-A*iv0)+off0
        inv1 = iv1; inv2 = iv2; inv3 = iv3;
        off0 = bnb[0] - bnm[0] * iv0;
        off1 = bnb[1] - bnm[1] * iv1;
        off2 = bnb[2] - bnm[2] * iv2;
        off3 = bnb[3] - bnm[3] * iv3;
    }

    // ---- per-lane weight fragments ----
    bf16x8 a1;
#pragma unroll
    for (int jp = 0; jp < 8; ++jp) {
        int j = quad + 4 * (jp >> 2);
        int c = jp & 3;
        float v = (n < 8 && j < 7) ? w1[(n * 4 + c) * 7 + j] : 0.0f;
        a1[jp] = (short)f2bf(v);
    }
    bf16x8 a20, a21;
#pragma unroll
    for (int jp = 0; jp < 8; ++jp) {
        float v0 = w2[(n * 8 + jp) * 5 + quad];
        float v1 = (quad + 4 < 5) ? w2[(n * 8 + jp) * 5 + quad + 4] : 0.0f;
        a20[jp] = (short)f2bf(v0);
        a21[jp] = (short)f2bf(v1);
    }
    f32x4 cb1, cb2;   // bias seeded into MFMA C operand
#pragma unroll
    for (int r = 0; r < 4; ++r) {
        cb1[r] = b1[(quad * 4 + r) & 7];
        cb2[r] = b2[quad * 4 + r];
    }

    float s_ing = 0.0f, s_fb = 0.0f;
    float m0 = 0.f, m1 = 0.f, m2 = 0.f, m3 = 0.f;

    // trapz AUC samples early (scattered fp32 loads; overlap their latency)
    float s_auc = 0.0f;
    if (tid < 200) {
        float pos = (float)tid * (2000.0f / 199.0f);
        int i0 = (int)pos;
        if (i0 > 2000) i0 = 2000;
        int i1 = (i0 + 1 < L_LEN) ? i0 + 1 : 2000;
        float w  = pos - (float)i0;
        float d0 = fmaxf(-primary[base + i0], 0.f);
        float d1 = fmaxf(-primary[base + i1], 0.f);
        float v  = d0 * (1.0f - w) + d1 * w;
        float wt = (tid == 0 || tid == 199) ? 0.5f : 1.0f;
        s_auc = v * wt;
    }

    // ---- stage A record processor ----
    auto aRec = [&](int m, int p, bool chk) {
        bool valid = true, core = true;
        int pc = p;
        if (chk) {
            valid = ((unsigned)p < (unsigned)L_LEN);
            core  = valid && (m >= 16) && (m < 16 + CCH);
            pc = min(max(p, 0), L_LEN - 1);
        }
        float ph = phase[base + pc];
        float pf = primary[base + pc];
        float sf = secondary[base + pc];
        float oe = oddeven[base + pc];
        float dd = ph - t0;
        float g  = fmaxf(fmaf(dd * dd, nBp, 1.0f), 0.0f);
        float x0 = fmaf(g,  gInv0, off0);
        float x1 = fmaf(pf, inv1, off1);
        float x2 = fmaf(sf, inv2, off2);
        float x3 = fmaf(oe, inv3, off3);
        unsigned d0 = bfpack(x0, x1);
        unsigned d1 = bfpack(x2, x3);
        if (chk && !valid) { d0 = 0u; d1 = 0u; }
        *(uint2*)&xs_i[2 * m] = make_uint2(d0, d1);
        // soft-mask features (total==1+1e-8 -> 1.0f exactly in fp32; skip the division)
        float depth = fmaxf(-pf, 0.0f);
        float e   = fexp2(depth * cExp);                    // exp(-50*dn)
        float dip = fast_rcp(fmaf(e, 148.413159f, 1.0f));   // sigm(50(dn-0.1))
        float fb  = fast_rcp(fmaf(e, 2.35385267e17f, 1.0f));// sigm(50(dn-0.8))
        float ing = dip - fb;
        if (chk && !core) { ing = 0.f; fb = 0.f; }
        s_ing += ing;
        s_fb  += fb;
    };

    auto stageA0 = [&]() {               // c0 = 0
        aRec(tid, tid - 16, true);                                    // lo straddle
#pragma unroll
        for (int k = 1; k < 4; ++k) aRec(tid + 256 * k, tid + 256 * k - 16, false);
        if (tid < 32) aRec(1024 + tid, 1008 + tid, true);             // tail (core split)
    };
    auto stageA1 = [&]() {               // c0 = 1024; xs records >= 1004 unused by stage B
        aRec(tid, 1008 + tid, true);                                  // m<16 non-core
#pragma unroll
        for (int k = 1; k < 3; ++k) aRec(tid + 256 * k, 1008 + tid + 256 * k, false);
        aRec(tid + 768, 1776 + tid, true);                            // hi straddle
    };

    // ---- stage B: conv1 via MFMA -> y1 ----
    auto stageB = [&](int c0, int nt, int straddle_t) {
        for (int t = wid; t < nt; t += 4) {
            int qb = 16 * t + n + quad + 5;
            FragU bu;
            bu.u2[0] = *(const uint2*)&xs_i[2 * qb];
            bu.u2[1] = *(const uint2*)&xs_i[2 * (qb + 4)];
            f32x4 d = __builtin_amdgcn_mfma_f32_16x16x32_bf16(a1, bu.v, cb1, 0, 0, 0);
            if (lane < 32) {                      // D rows 0..7 hold the 8 oc
                int q = 16 * t + n;
                unsigned w0, w1_;
                if (t == straddle_t) {            // wave-uniform branch
                    int p = c0 - 8 + q;
                    bool ok = ((unsigned)p < (unsigned)L_LEN);
                    w0  = ok ? bfpack(fmaxf(d[0], 0.f), fmaxf(d[1], 0.f)) : 0u;
                    w1_ = ok ? bfpack(fmaxf(d[2], 0.f), fmaxf(d[3], 0.f)) : 0u;
                } else {
                    w0  = bfpack(fmaxf(d[0], 0.f), fmaxf(d[1], 0.f));
                    w1_ = bfpack(fmaxf(d[2], 0.f), fmaxf(d[3], 0.f));
                }
                *(uint2*)&y1_i[4 * q + 2 * quad] = make_uint2(w0, w1_);
            }
        }
    };

    // ---- stage C: conv2 via MFMA, accumulate channel sums ----
    auto stageC = [&](int nt, bool maskLast) {
        for (int t = wid; t < nt; t += 4) {
            int q = 16 * t + n + quad + 6;
            FragU u0, u1;
            u0.u4 = *(const uint4*)&y1_i[4 * q];
            u1.u4 = *(const uint4*)&y1_i[4 * (q + 4)];
            f32x4 d = __builtin_amdgcn_mfma_f32_16x16x32_bf16(a20, u0.v, cb2, 0, 0, 0);
            d = __builtin_amdgcn_mfma_f32_16x16x32_bf16(a21, u1.v, d, 0, 0, 0);
            if (maskLast && t == 61) {            // outputs 2000..2015: only n==0 valid
                float msk = (n == 0) ? 1.0f : 0.0f;
                m0 = fmaf(fmaxf(d[0], 0.f), msk, m0);
                m1 = fmaf(fmaxf(d[1], 0.f), msk, m1);
                m2 = fmaf(fmaxf(d[2], 0.f), msk, m2);
                m3 = fmaf(fmaxf(d[3], 0.f), msk, m3);
            } else {
                m0 += fmaxf(d[0], 0.f);
                m1 += fmaxf(d[1], 0.f);
                m2 += fmaxf(d[2], 0.f);
                m3 += fmaxf(d[3], 0.f);
            }
        }
    };

    // ---- pipeline: A0 | B0 | {A1, C0} | B1 | C1 ----
    stageA0();
    __syncthreads();           // xs(0) ready
    stageB(0, 65, 0);
    __syncthreads();           // y1(0) ready; xs free
    stageA1();                 // xs(1) write overlaps C0's y1 reads (disjoint)
    stageC(64, false);
    __syncthreads();           // xs(1) ready; y1 free
    stageB(1024, 62, 61);
    __syncthreads();           // y1(1) ready
    stageC(62, true);

    // ---- reductions ----
#pragma unroll
    for (int dlt = 8; dlt >= 1; dlt >>= 1) {
        m0 += __shfl_xor(m0, dlt);
        m1 += __shfl_xor(m1, dlt);
        m2 += __shfl_xor(m2, dlt);
        m3 += __shfl_xor(m3, dlt);
    }
    if ((lane & 15) == 0) {
        redA[wid][quad * 4 + 0] = m0;
        redA[wid][quad * 4 + 1] = m1;
        redA[wid][quad * 4 + 2] = m2;
        redA[wid][quad * 4 + 3] = m3;
    }
#pragma unroll
    for (int dlt = 32; dlt >= 1; dlt >>= 1) {
        s_ing += __shfl_xor(s_ing, dlt);
        s_fb  += __shfl_xor(s_fb,  dlt);
        s_auc += __shfl_xor(s_auc, dlt);
    }
    if (lane == 0) {
        redB[wid][0] = s_ing;
        redB[wid][1] = s_fb;
        redB[wid][2] = s_auc;
    }
    __syncthreads();

    if (tid == 0) {
        float logit = fcb[0];
#pragma unroll
        for (int oc = 0; oc < 16; ++oc) {
            float s = redA[0][oc] + redA[1][oc] + redA[2][oc] + redA[3][oc];
            logit += (s / 2001.0f) * fcw[oc];
        }
        float Sing = redB[0][0] + redB[1][0] + redB[2][0] + redB[3][0];
        float Sfb  = redB[0][1] + redB[1][1] + redB[2][1] + redB[3][1];
        float Sauc = redB[0][2] + redB[1][2] + redB[2][2] + redB[3][2];

        float auc_raw  = (float)(2.0 / 199.0) * Sauc;
        float auc_norm = auc_raw / A_abs;
        float m_ing = Sing / 2001.0f;
        float m_fb  = Sfb  / 2001.0f;
        float t14   = (Sing + Sfb) / 2001.0f + 1e-8f;
        float t12   = m_ing / t14;

        logit += Bp       * fcw[16]
               + auc_raw  * fcw[17]
               + auc_norm * fcw[18]
               + t12      * fcw[19]
               + m_fb     * fcw[20];

        out[row] = 1.0f / (1.0f + expf(-logit));
    }
}

extern "C" void kernel_launch(void* const* d_in, const int* in_sizes, int n_in,
                              void* d_out, int out_size, void* d_ws, size_t ws_size,
                              hipStream_t stream) {
    const float* phase     = (const float*)d_in[0];
    const float* primary   = (const float*)d_in[1];
    const float* secondary = (const float*)d_in[2];
    const float* oddeven   = (const float*)d_in[3];
    const float* pA        = (const float*)d_in[4];
    const float* pBp       = (const float*)d_in[5];
    const float* pT0       = (const float*)d_in[6];
    const float* bng       = (const float*)d_in[7];
    const float* bnb       = (const float*)d_in[8];
    const float* bnm       = (const float*)d_in[9];
    const float* bnv       = (const float*)d_in[10];
    const float* w1        = (const float*)d_in[11];
    const float* b1        = (const float*)d_in[12];
    const float* w2        = (const float*)d_in[13];
    const float* b2        = (const float*)d_in[14];
    const float* fcw       = (const float*)d_in[15];
    const float* fcb       = (const float*)d_in[16];
    float* out = (float*)d_out;

    int nrows = in_sizes[0] / L_LEN;   // 8192
    dim3 grid(nrows), block(256);
    hipLaunchKernelGGL(taylor_cnn_v8_mfma, grid, block, 0, stream,
                       phase, primary, secondary, oddeven, pA, pBp, pT0,
                       bng, bnb, bnm, bnv, w1, b1, w2, b2, fcw, fcb, out, nrows);
}